// Round 5
// baseline (921.494 us; speedup 1.0000x reference)
//
#include <hip/hip_runtime.h>
#include <hip/hip_bf16.h>
#include <stdint.h>

// Problem constants
#define SEQ   8192
#define HDIM  3072
#define NWIN  19
#define WINL  512
#define STR   448
#define NHEAD 12
#define DHEAD 256
#define QKVN  9216
#define ATTN_SCALE 0.0625f

typedef unsigned short u16;
typedef __bf16 bf16x8 __attribute__((ext_vector_type(8)));
typedef float  f32x4  __attribute__((ext_vector_type(4)));
typedef unsigned short us8 __attribute__((ext_vector_type(8)));

__device__ __forceinline__ u16 f2b(float x) {
  return __builtin_bit_cast(u16, __float2bfloat16(x));
}
__device__ __forceinline__ float b2f(u16 u) {
  return __builtin_bit_cast(float, (unsigned int)(u) << 16);
}
__device__ __forceinline__ void gload_lds16(const void* g, void* l) {
  __builtin_amdgcn_global_load_lds(
      (const __attribute__((address_space(1))) void*)g,
      (__attribute__((address_space(3))) void*)l, 16, 0, 0);
}

// ---------------- elementwise converts ----------------
__global__ __launch_bounds__(256) void cvt_f32_bf16(const float* __restrict__ src,
                                                    u16* __restrict__ dst, int n8) {
  int i = blockIdx.x * 256 + threadIdx.x;
  if (i >= n8) return;
  const float4* s4 = (const float4*)src;
  float4 a = s4[2 * i], b = s4[2 * i + 1];
  us8 o;
  o[0] = f2b(a.x); o[1] = f2b(a.y); o[2] = f2b(a.z); o[3] = f2b(a.w);
  o[4] = f2b(b.x); o[5] = f2b(b.y); o[6] = f2b(b.z); o[7] = f2b(b.w);
  *((us8*)dst + i) = o;
}

__global__ __launch_bounds__(256) void biascat(const float* __restrict__ bq,
                                               const float* __restrict__ bk,
                                               const float* __restrict__ bv,
                                               float* __restrict__ dst) {
  int i = blockIdx.x * 256 + threadIdx.x;
  if (i >= QKVN) return;
  dst[i] = (i < HDIM) ? bq[i] : ((i < 2 * HDIM) ? bk[i - HDIM] : bv[i - 2 * HDIM]);
}

// ---------------- 256x256 counted-wait pipelined GEMM: C = A * B^T (+bias) ----------------
// A[M][K] bf16 row-major, B[N][K] bf16 row-major. K-subtile BK=32.
// 8 waves (2Mx4N), per-wave C = 128x64 (rows wm*128+mi*16+fr, cols wn*64+ni*16).
// LDS: ring of 4 subtile slots [256][32] per operand = 128 KiB (1 block/CU).
// 16B-chunk swizzle: phys_chunk = logical ^ ((row>>1)&3), both sides (Round-3-verified).
//
// Schedule per subtile T (ONE barrier; counted waits; wave-slip overlap):
//   [entry: reads(T)=12 outstanding (issued after T-1's barrier, groups 6/2/2/2);
//    stage(T+1)=4 vm-outstanding (issued during T-1)]
//   stage(T+2) -> slot (T+2)&3                      (4 gloads, cond)
//   lgkmcnt(6): g1 {af0,af1,bf0-3} done -> 8 MFMA (mi0,1 x ni0-3)
//   lgkmcnt(4): g2 {af2,af3}          -> 8 MFMA (mi2,3)
//   lgkmcnt(2): g3 {af4,af5}          -> 8 MFMA (mi4,5)
//   lgkmcnt(0): g4 {af6,af7}          -> 8 MFMA (mi6,7)
//   vmcnt(4 | 0 at tail): stage(T+1) complete (own share)
//   s_barrier: all waves' stage(T+1) visible; then issue reads(T+1).
// Race-freedom:
//  - slot (T+2)&3 write vs reads: its last reads (subtile T-2) were drained by
//    each wave's lgkmcnt(0) before T-2's end barrier, 2 barriers before this
//    staging issue.
//  - reads(T+1) vs staging: own-wave vmcnt + barrier makes ALL waves' T+1
//    staging visible before any wave issues reads(T+1).
//  - sched_barrier(0) after each wait and between issue groups pins program
//    order (rule: compiler may hoist reg-only MFMA past inline-asm waits).
template <bool BF16OUT>
__global__ __launch_bounds__(512, 2) void gemm256(const u16* __restrict__ A,
                                                  const u16* __restrict__ B,
                                                  const float* __restrict__ bias,
                                                  float* __restrict__ outF,
                                                  u16* __restrict__ outB,
                                                  int N, int K) {
  __shared__ __align__(16) u16 As[4][8192];
  __shared__ __align__(16) u16 Bs[4][8192];
  const int tid = threadIdx.x;
  const int w = tid >> 6, l = tid & 63;
  const int wm = w >> 2, wn = w & 3;
  const int fr = l & 15, g = l >> 4;
  // XCD-band mapping (assumes hardware round-robin bid->XCD = bid%8);
  // nbm = M/256 = 32 = 8 XCDs x 4 rows for both GEMMs.
  const int xcd = blockIdx.x & 7, loc = blockIdx.x >> 3;
  const int bn = loc >> 2, bm = xcd * 4 + (loc & 3);

  const u16* Ab = A + (size_t)bm * 256 * K;
  const u16* Bb = B + (size_t)bn * 256 * K;

  // staging: thread writes slot bytes h*8192... wait slot is 16KB: h*8192 + w*1024 + l*16,
  // rows h*128 + w*16 + (l>>2), phys chunk l&3; source col chunk inverse-swizzled.
  const int r_st = w * 16 + (l >> 2);
  const int s_st = ((l & 3) ^ ((l >> 3) & 3)) * 8;
  // fragment read: row = base+fr, phys chunk = g ^ ((fr>>1)&3)
  const int sw = (g ^ ((fr >> 1) & 3)) * 8;

  f32x4 acc[8][4];
#pragma unroll
  for (int i = 0; i < 8; ++i)
#pragma unroll
    for (int j = 0; j < 4; ++j) acc[i][j] = (f32x4){0.f, 0.f, 0.f, 0.f};

  auto stA = [&](int T) {
    char* d = (char*)&As[T & 3][0] + w * 1024 + l * 16;
    const u16* s = Ab + (size_t)r_st * K + T * 32 + s_st;
    gload_lds16(s, d);
    gload_lds16(s + (size_t)128 * K, d + 8192);
  };
  auto stB = [&](int T) {
    char* d = (char*)&Bs[T & 3][0] + w * 1024 + l * 16;
    const u16* s = Bb + (size_t)r_st * K + T * 32 + s_st;
    gload_lds16(s, d);
    gload_lds16(s + (size_t)128 * K, d + 8192);
  };

  bf16x8 af[8], bf[4];
  auto issue_reads = [&](int U) {
    const u16* as_ = &As[U & 3][0] + (wm * 128 + fr) * 32 + sw;
    const u16* bs_ = &Bs[U & 3][0] + (wn * 64 + fr) * 32 + sw;
    // g1 (6): af0, af1, bf0-3
    af[0] = *(const bf16x8*)(as_);
    af[1] = *(const bf16x8*)(as_ + 512);
    bf[0] = *(const bf16x8*)(bs_);
    bf[1] = *(const bf16x8*)(bs_ + 512);
    bf[2] = *(const bf16x8*)(bs_ + 1024);
    bf[3] = *(const bf16x8*)(bs_ + 1536);
    __builtin_amdgcn_sched_barrier(0);
    // g2 (2)
    af[2] = *(const bf16x8*)(as_ + 1024);
    af[3] = *(const bf16x8*)(as_ + 1536);
    __builtin_amdgcn_sched_barrier(0);
    // g3 (2)
    af[4] = *(const bf16x8*)(as_ + 2048);
    af[5] = *(const bf16x8*)(as_ + 2560);
    __builtin_amdgcn_sched_barrier(0);
    // g4 (2)
    af[6] = *(const bf16x8*)(as_ + 3072);
    af[7] = *(const bf16x8*)(as_ + 3584);
    __builtin_amdgcn_sched_barrier(0);
  };

  // prologue: stage subtiles 0,1; drain slot0; issue reads(0)
  stA(0); stB(0); stA(1); stB(1);
  asm volatile("s_waitcnt vmcnt(4)" ::: "memory");
  __builtin_amdgcn_s_barrier();
  __builtin_amdgcn_sched_barrier(0);
  issue_reads(0);

  const int NT = K >> 5;
  for (int T = 0; T < NT; ++T) {
    if (T + 2 < NT) { stA(T + 2); stB(T + 2); }
    asm volatile("s_waitcnt lgkmcnt(6)" ::: "memory");
    __builtin_amdgcn_sched_barrier(0);
    __builtin_amdgcn_s_setprio(1);
#pragma unroll
    for (int mi = 0; mi < 2; ++mi)
#pragma unroll
      for (int ni = 0; ni < 4; ++ni)
        acc[mi][ni] = __builtin_amdgcn_mfma_f32_16x16x32_bf16(af[mi], bf[ni], acc[mi][ni], 0, 0, 0);
    __builtin_amdgcn_s_setprio(0);
    asm volatile("s_waitcnt lgkmcnt(4)" ::: "memory");
    __builtin_amdgcn_sched_barrier(0);
    __builtin_amdgcn_s_setprio(1);
#pragma unroll
    for (int mi = 2; mi < 4; ++mi)
#pragma unroll
      for (int ni = 0; ni < 4; ++ni)
        acc[mi][ni] = __builtin_amdgcn_mfma_f32_16x16x32_bf16(af[mi], bf[ni], acc[mi][ni], 0, 0, 0);
    __builtin_amdgcn_s_setprio(0);
    asm volatile("s_waitcnt lgkmcnt(2)" ::: "memory");
    __builtin_amdgcn_sched_barrier(0);
    __builtin_amdgcn_s_setprio(1);
#pragma unroll
    for (int mi = 4; mi < 6; ++mi)
#pragma unroll
      for (int ni = 0; ni < 4; ++ni)
        acc[mi][ni] = __builtin_amdgcn_mfma_f32_16x16x32_bf16(af[mi], bf[ni], acc[mi][ni], 0, 0, 0);
    __builtin_amdgcn_s_setprio(0);
    asm volatile("s_waitcnt lgkmcnt(0)" ::: "memory");
    __builtin_amdgcn_sched_barrier(0);
    __builtin_amdgcn_s_setprio(1);
#pragma unroll
    for (int mi = 6; mi < 8; ++mi)
#pragma unroll
      for (int ni = 0; ni < 4; ++ni)
        acc[mi][ni] = __builtin_amdgcn_mfma_f32_16x16x32_bf16(af[mi], bf[ni], acc[mi][ni], 0, 0, 0);
    __builtin_amdgcn_s_setprio(0);
    if (T < NT - 1) {
      if (T + 2 < NT) asm volatile("s_waitcnt vmcnt(4)" ::: "memory");
      else            asm volatile("s_waitcnt vmcnt(0)" ::: "memory");
      __builtin_amdgcn_s_barrier();
      __builtin_amdgcn_sched_barrier(0);
      issue_reads(T + 1);
    }
  }

  // epilogue
#pragma unroll
  for (int ni = 0; ni < 4; ++ni) {
    const int c = bn * 256 + wn * 64 + ni * 16 + fr;
    const float bvv = bias ? bias[c] : 0.0f;
#pragma unroll
    for (int mi = 0; mi < 8; ++mi) {
      const int r0 = bm * 256 + wm * 128 + mi * 16 + g * 4;
#pragma unroll
      for (int jj = 0; jj < 4; ++jj) {
        float v = acc[mi][ni][jj] + bvv;
        if (BF16OUT) outB[(size_t)(r0 + jj) * N + c] = f2b(v);
        else         outF[(size_t)(r0 + jj) * N + c] = v;
      }
    }
  }
}

// ---------------- V transpose: Vt[3072][8192] <- QKV[:, 6144+c] ----------------
__global__ __launch_bounds__(256) void vtrans(const u16* __restrict__ QKV,
                                              u16* __restrict__ Vt) {
  __shared__ u16 t[64][72];
  const int tid = threadIdx.x;
  const int s0 = blockIdx.x * 64, c0 = blockIdx.y * 64;
  {
    const int r2 = tid >> 3, cc = (tid & 7) * 8;
#pragma unroll
    for (int p = 0; p < 2; ++p) {
      const int row = r2 + p * 32;
      u16 tmp[8];
      *(uint4*)tmp = *(const uint4*)(QKV + (size_t)(s0 + row) * QKVN + 2 * HDIM + c0 + cc);
#pragma unroll
      for (int j = 0; j < 8; ++j) t[row][cc + j] = tmp[j];
    }
  }
  __syncthreads();
  {
    const int cr2 = tid >> 3, sc = tid & 7;
#pragma unroll
    for (int p = 0; p < 2; ++p) {
      const int c = cr2 + p * 32;
      u16 tmp[8];
#pragma unroll
      for (int j = 0; j < 8; ++j) tmp[j] = t[sc * 8 + j][c];
      *(uint4*)(Vt + (size_t)(c0 + c) * SEQ + s0 + sc * 8) = *(uint4*)tmp;
    }
  }
}

// ---------------- windowed flash attention ----------------
// grid (8 qb, 12 h, 19 win), 4 waves. Each wave: 16 q-rows, online softmax over 8 chunks of 64 kv.
__global__ __launch_bounds__(256, 2) void attn_kernel(const u16* __restrict__ QKV,
                                                      const u16* __restrict__ Vt,
                                                      u16* __restrict__ ctxw) {
  __shared__ __align__(16) u16 Ks[64 * 256];   // [kv][d], chunk-swizzled (XOR row&31 on 16B chunks)
  __shared__ __align__(16) u16 Vts[256 * 64];  // [d][kv], chunk-swizzled (XOR row&7)
  __shared__ __align__(16) u16 Ps[4][16 * 64]; // per-wave P scratch, XOR (q&7)<<4 byte swizzle
  const int qb = blockIdx.x, h = blockIdx.y, n = blockIdx.z;
  const int tid = threadIdx.x, w = tid >> 6, l = tid & 63;
  const int g = l >> 4, fr = l & 15;
  const int s0 = n * STR;

  // Q fragments (16 rows per wave) straight from global
  bf16x8 qf[8];
  {
    int sq = s0 + qb * 64 + w * 16 + fr;
    if (sq > SEQ - 1) sq = SEQ - 1;
    const u16* qbase = QKV + (size_t)sq * QKVN + h * DHEAD + g * 8;
#pragma unroll
    for (int dc = 0; dc < 8; ++dc) qf[dc] = *(const bf16x8*)(qbase + dc * 32);
  }
  f32x4 ctx[16];
#pragma unroll
  for (int dn = 0; dn < 16; ++dn) ctx[dn] = (f32x4){0.f, 0.f, 0.f, 0.f};
  float mrow[4] = {-3e38f, -3e38f, -3e38f, -3e38f};
  float lrow[4] = {0.f, 0.f, 0.f, 0.f};

  const int kr_in = l >> 5;  // K staging: row within 2-row chunk
  const int kcp = l & 31;    // K staging: physical 16B chunk in row
  const int vr_in = l >> 3;  // V staging: row within 8-row chunk
  const int vcp = l & 7;

  for (int kt = 0; kt < 8; ++kt) {
    const int sb = s0 + kt * 64;
    // ---- stage K[64][256] and Vt-slice[256][64], source pre-swizzled ----
#pragma unroll
    for (int i = 0; i < 8; ++i) {
      const int c = i * 4 + w;  // 1KB chunk id, 0..31
      {
        const int krow = c * 2 + kr_in;
        const int cl = kcp ^ (krow & 31);
        int sk = sb + krow;
        if (sk > SEQ - 1) sk = SEQ - 1;
        gload_lds16(QKV + (size_t)sk * QKVN + HDIM + h * DHEAD + cl * 8, (char*)Ks + c * 1024);
      }
      {
        const int d = c * 8 + vr_in;
        const int cl = vcp ^ (d & 7);
        int sv = sb + cl * 8;
        if (sv > SEQ - 8) sv = SEQ - 8;
        gload_lds16(Vt + (size_t)(h * DHEAD + d) * SEQ + sv, (char*)Vts + c * 1024);
      }
    }
    __syncthreads();

    // ---- S = Q K^T (rows q=(g*4+r), cols kv=kn*16+fr) ----
    f32x4 sacc[4];
#pragma unroll
    for (int kn = 0; kn < 4; ++kn) sacc[kn] = (f32x4){0.f, 0.f, 0.f, 0.f};
#pragma unroll
    for (int kn = 0; kn < 4; ++kn) {
      const int krow = kn * 16 + fr;
      const char* krp = (const char*)Ks + krow * 512;
      const int rx = krow & 31;
#pragma unroll
      for (int dc = 0; dc < 8; ++dc) {
        bf16x8 kf = *(const bf16x8*)(krp + (((dc * 4 + g) ^ rx) << 4));
        sacc[kn] = __builtin_amdgcn_mfma_f32_16x16x32_bf16(qf[dc], kf, sacc[kn], 0, 0, 0);
      }
    }
    // ---- scale + validity mask + online softmax ----
    float mt[4];
#pragma unroll
    for (int kn = 0; kn < 4; ++kn) {
      const bool valid = (sb + kn * 16 + fr) < SEQ;
#pragma unroll
      for (int r = 0; r < 4; ++r) {
        float v = valid ? sacc[kn][r] * ATTN_SCALE : -1e9f;
        sacc[kn][r] = v;
        mt[r] = (kn == 0) ? v : fmaxf(mt[r], v);
      }
    }
#pragma unroll
    for (int r = 0; r < 4; ++r) {
#pragma unroll
      for (int off = 1; off < 16; off <<= 1)
        mt[r] = fmaxf(mt[r], __shfl_xor(mt[r], off, 64));
    }
    float corr[4];
#pragma unroll
    for (int r = 0; r < 4; ++r) {
      float mnew = fmaxf(mrow[r], mt[r]);
      corr[r] = __expf(mrow[r] - mnew);
      mrow[r] = mnew;
    }
    float psum[4] = {0.f, 0.f, 0.f, 0.f};
    char* pw = (char*)&Ps[w][0];
#pragma unroll
    for (int kn = 0; kn < 4; ++kn) {
#pragma unroll
      for (int r = 0; r < 4; ++r) {
        float p = __expf(sacc[kn][r] - mrow[r]);
        psum[r] += p;
        const int q = g * 4 + r;
        *(u16*)(pw + q * 128 + ((2 * (kn * 16 + fr)) ^ ((q & 7) << 4))) = f2b(p);
      }
    }
#pragma unroll
    for (int r = 0; r < 4; ++r) {
#pragma unroll
      for (int off = 1; off < 16; off <<= 1)
        psum[r] += __shfl_xor(psum[r], off, 64);
      lrow[r] = lrow[r] * corr[r] + psum[r];
    }
#pragma unroll
    for (int dn = 0; dn < 16; ++dn)
#pragma unroll
      for (int r = 0; r < 4; ++r) ctx[dn][r] *= corr[r];
    __syncthreads();  // Ps visible (and ordered) before fragment reads

    // ---- ctx += P * V (via Vt rows as B^T) ----
    bf16x8 pf[2];
#pragma unroll
    for (int kc = 0; kc < 2; ++kc)
      pf[kc] = *(const bf16x8*)(pw + fr * 128 + ((kc * 64 + g * 16) ^ ((fr & 7) << 4)));
#pragma unroll
    for (int dn = 0; dn < 16; ++dn) {
      const int d = dn * 16 + fr;
      const char* vrp = (const char*)Vts + d * 128;
      const int dx = d & 7;
#pragma unroll
      for (int kc = 0; kc < 2; ++kc) {
        bf16x8 vf = *(const bf16x8*)(vrp + (((kc * 4 + g) ^ dx) << 4));
        ctx[dn] = __builtin_amdgcn_mfma_f32_16x16x32_bf16(pf[kc], vf, ctx[dn], 0, 0, 0);
      }
    }
    __syncthreads();  // all waves done with Ks/Vts before next stage
  }
  // ---- epilogue: normalize and store ctx ----
  float inv[4];
#pragma unroll
  for (int r = 0; r < 4; ++r) inv[r] = 1.0f / lrow[r];
  const int qrow0 = qb * 64 + w * 16 + g * 4;
#pragma unroll
  for (int dn = 0; dn < 16; ++dn) {
#pragma unroll
    for (int r = 0; r < 4; ++r) {
      ctxw[(size_t)(n * WINL + qrow0 + r) * HDIM + h * DHEAD + dn * 16 + fr] =
          f2b(ctx[dn][r] * inv[r]);
    }
  }
}

// ---------------- overlap-average combine: ctx_avg[8192][3072] ----------------
__global__ __launch_bounds__(256) void combine_kernel(const u16* __restrict__ ctxw,
                                                      u16* __restrict__ ctx_avg) {
  int idx = blockIdx.x * 256 + threadIdx.x;
  if (idx >= SEQ * (HDIM / 8)) return;
  const int s = idx / (HDIM / 8);
  const int cc = (idx % (HDIM / 8)) * 8;
  const int w1 = s / STR;          // <= 18
  const int off1 = s - w1 * STR;   // 0..447
  us8 a = *(const us8*)(ctxw + (size_t)(w1 * WINL + off1) * HDIM + cc);
  if (w1 >= 1 && off1 < (WINL - STR)) {
    us8 b = *(const us8*)(ctxw + (size_t)((w1 - 1) * WINL + off1 + STR) * HDIM + cc);
#pragma unroll
    for (int j = 0; j < 8; ++j) a[j] = f2b(0.5f * (b2f(a[j]) + b2f(b[j])));
  }
  *(us8*)(ctx_avg + (size_t)s * HDIM + cc) = a;
}

__global__ void ws_marker(float* out, float v) { out[0] = v; }

// ---------------- launch ----------------
extern "C" void kernel_launch(void* const* d_in, const int* in_sizes, int n_in,
                              void* d_out, int out_size, void* d_ws, size_t ws_size,
                              hipStream_t stream) {
  const float* X  = (const float*)d_in[0];
  const float* Wq = (const float*)d_in[1];
  const float* bq = (const float*)d_in[2];
  const float* Wk = (const float*)d_in[3];
  const float* bk = (const float*)d_in[4];
  const float* Wv = (const float*)d_in[5];
  const float* bv = (const float*)d_in[6];
  const float* Wo = (const float*)d_in[7];
  const float* bo = (const float*)d_in[8];
  float* out = (float*)d_out;

  // workspace layout (bytes)
  const size_t OFF_XB   = 0;                          // 8192*3072*2   = 50331648
  const size_t OFF_WQKV = 50331648;                   // 9216*3072*2   = 56623104
  const size_t OFF_WO   = 106954752;                  // 3072*3072*2   = 18874368
  const size_t OFF_QKV  = 125829120;                  // 8192*9216*2   = 150994944
  const size_t OFF_VT   = 276824064;                  // 3072*8192*2   = 50331648
  const size_t OFF_BIAS = 327155712;                  // 9216*4        = 36864
  const size_t WS_NEED  = 327192576;
  if (ws_size < WS_NEED) {
    hipMemsetAsync(d_out, 0, (size_t)out_size * 4, stream);
    ws_marker<<<1, 1, 0, stream>>>(out, (float)(ws_size / 1048576));
    return;
  }
  char* ws = (char*)d_ws;
  u16* Xb      = (u16*)(ws + OFF_XB);
  u16* Wqkvb   = (u16*)(ws + OFF_WQKV);
  u16* Wob     = (u16*)(ws + OFF_WO);
  u16* QKV     = (u16*)(ws + OFF_QKV);
  u16* Vt      = (u16*)(ws + OFF_VT);
  float* biasQ = (float*)(ws + OFF_BIAS);
  u16* ctxw    = (u16*)d_out;  // 59.8MB scratch inside the 100.7MB output buffer
  u16* ctx_avg = Xb;           // alias: Xb dead after QKV GEMM

  cvt_f32_bf16<<<12288, 256, 0, stream>>>(X, Xb, SEQ * HDIM / 8);
  cvt_f32_bf16<<<4608, 256, 0, stream>>>(Wq, Wqkvb, HDIM * HDIM / 8);
  cvt_f32_bf16<<<4608, 256, 0, stream>>>(Wk, Wqkvb + (size_t)HDIM * HDIM, HDIM * HDIM / 8);
  cvt_f32_bf16<<<4608, 256, 0, stream>>>(Wv, Wqkvb + (size_t)2 * HDIM * HDIM, HDIM * HDIM / 8);
  cvt_f32_bf16<<<4608, 256, 0, stream>>>(Wo, Wob, HDIM * HDIM / 8);
  biascat<<<36, 256, 0, stream>>>(bq, bk, bv, biasQ);

  gemm256<true><<<dim3((SEQ / 256) * (QKVN / 256)), 512, 0, stream>>>(
      Xb, Wqkvb, biasQ, nullptr, QKV, QKVN, HDIM);

  vtrans<<<dim3(SEQ / 64, HDIM / 64), 256, 0, stream>>>(QKV, Vt);

  attn_kernel<<<dim3(8, NHEAD, NWIN), 256, 0, stream>>>(QKV, Vt, ctxw);

  combine_kernel<<<12288, 256, 0, stream>>>(ctxw, ctx_avg);

  gemm256<false><<<dim3((SEQ / 256) * (HDIM / 256)), 512, 0, stream>>>(
      ctx_avg, Wob, bo, out, nullptr, HDIM, HDIM);
}